// Round 13
// baseline (41.187 us; speedup 1.0000x reference)
//
#include <hip/hip_runtime.h>
#include <cstddef>
#include <cstdint>

#define BDIM 4
#define HH   64
#define WW   64
#define NG   4
#define GD   64
#define HWSZ 4096
#define NTOT 16384          // BDIM*HWSZ
#define CIN  256

typedef __attribute__((ext_vector_type(4))) float f32x4;
typedef _Float16 f16x4_t __attribute__((ext_vector_type(4)));
typedef _Float16 f16x8_t __attribute__((ext_vector_type(8)));

// ---------- fused QKV GEMM: persistent-A fp16 LDS, K split in 2 passes ----------
// D[768 x 16384] = W[768 x 256] * x[256 x 16384]. 128x128 tile, 4 waves,
// BK=32, 8 K-steps (2 passes x 4). A converted fp32->fp16 ONCE per pass into
// persistent LDS [128m][128k] (slot ^= m&15 swizzle, 2-way free). B reg-staged
// fp16 double-buffer as R12 (slot ^= px&3). LDS 48 KB -> 3 blocks/CU.
__global__ __launch_bounds__(256, 3) void qkv_gemm_kernel(
    const float* __restrict__ x,
    const float* __restrict__ wq, const float* __restrict__ bq,
    const float* __restrict__ wk, const float* __restrict__ bk,
    const float* __restrict__ wv, const float* __restrict__ bv,
    _Float16* __restrict__ qh, _Float16* __restrict__ kh,
    _Float16* __restrict__ vh)
{
    __shared__ _Float16 Ap[128 * 128];     // 32 KB persistent A (one K-pass)
    __shared__ _Float16 Bs[2][128 * 32];   // 2 x 8 KB B dbuf

    const int t  = threadIdx.x;
    const int bx = blockIdx.x;
    const int u  = (bx & 7) * 96 + (bx >> 3);   // XCD-chunked (768 = 8*96)
    const int mt = u % 6;                       // consecutive u share nt (x panel)
    const int nt = u / 6;                       // 0..127

    const int l     = t & 63;
    const int wid   = t >> 6;
    const int wm    = wid >> 1, wn = wid & 1;
    const int lrow  = l & 15;
    const int grp   = l >> 4;                   // koct 0..3
    const int lrow4 = grp * 4;

    const float* wsel = (mt < 2) ? wq : (mt < 4) ? wk : wv;
    const float* bsel = (mt < 2) ? bq : (mt < 4) ? bk : bv;
    _Float16*    osel = (mt < 2) ? qh : (mt < 4) ? kh : vh;
    const int    mtl  = mt & 1;

    const int bi  = nt >> 5;
    const int px0 = (nt & 31) * 128;

    // acc init with bias
    f32x4 acc[4][4];
    #pragma unroll
    for (int mi = 0; mi < 4; ++mi) {
        const f32x4 bb = *(const f32x4*)&bsel[mtl * 128 + wm * 64 + mi * 16 + lrow4];
        #pragma unroll
        for (int ni = 0; ni < 4; ++ni) acc[mi][ni] = bb;
    }

    // ---- A staging geometry: thread -> (row smA = t>>1, k-half khA = (t&1)*64) ----
    const int smA = t >> 1;
    const int khA = (t & 1) * 64;
    const float* wrow = wsel + (size_t)(mtl * 128 + smA) * CIN + khA;
    const int aswz = smA & 15;

    // ---- B staging: px = t&127, kocts {t>>7, (t>>7)+2} (R12 pattern) ----
    const int spx  = t & 127;
    const int sko0 = t >> 7;                 // 0..1
    const float* xbp = x + (size_t)bi * CIN * HWSZ + px0 + spx;
    const int bw0 = spx * 32 + ((sko0       ^ (spx & 3)) * 8);
    const int bw1 = spx * 32 + (((sko0 + 2) ^ (spx & 3)) * 8);

    // ---- stage A pass 0 (chunked: 4 x {4 float4 -> 2 slots}) ----
    #pragma unroll
    for (int c = 0; c < 4; ++c) {
        float fl[16];
        #pragma unroll
        for (int q4 = 0; q4 < 4; ++q4) {
            const float4 v = *(const float4*)(wrow + c * 16 + q4 * 4);
            fl[q4 * 4 + 0] = v.x; fl[q4 * 4 + 1] = v.y;
            fl[q4 * 4 + 2] = v.z; fl[q4 * 4 + 3] = v.w;
        }
        #pragma unroll
        for (int hs = 0; hs < 2; ++hs) {
            const int slot = (khA >> 3) + c * 2 + hs;
            f16x8_t w8;
            #pragma unroll
            for (int j = 0; j < 8; ++j) w8[j] = (_Float16)fl[hs * 8 + j];
            *(f16x8_t*)&Ap[smA * 128 + ((slot ^ aswz) << 3)] = w8;
        }
    }
    // ---- stage B step 0 ----
    {
        float r0[8], r1[8];
        #pragma unroll
        for (int j = 0; j < 8; ++j) r0[j] = xbp[(size_t)(sko0 * 8 + j) * HWSZ];
        #pragma unroll
        for (int j = 0; j < 8; ++j) r1[j] = xbp[(size_t)((sko0 + 2) * 8 + j) * HWSZ];
        f16x8_t w0, w1;
        #pragma unroll
        for (int j = 0; j < 8; ++j) { w0[j] = (_Float16)r0[j]; w1[j] = (_Float16)r1[j]; }
        *(f16x8_t*)&Bs[0][bw0] = w0;
        *(f16x8_t*)&Bs[0][bw1] = w1;
    }
    __syncthreads();

    #pragma unroll
    for (int s = 0; s < 8; ++s) {
        const int cur = s & 1, nxt = cur ^ 1;
        const int kt  = s & 3;

        // issue next-step B loads early
        float r0[8], r1[8];
        if (s < 7) {
            const int kb = (s + 1) * 32;
            #pragma unroll
            for (int j = 0; j < 8; ++j) r0[j] = xbp[(size_t)(kb + sko0 * 8 + j) * HWSZ];
            #pragma unroll
            for (int j = 0; j < 8; ++j) r1[j] = xbp[(size_t)(kb + (sko0 + 2) * 8 + j) * HWSZ];
        }

        // A fragments: single swizzled fp16 b128 per mi
        f16x8_t af[4], bf[4];
        #pragma unroll
        for (int mi = 0; mi < 4; ++mi) {
            const int m = wm * 64 + mi * 16 + lrow;
            af[mi] = *(const f16x8_t*)&Ap[m * 128 + (((kt * 4 + grp) ^ (m & 15)) << 3)];
        }
        // B fragments: single swizzled b128 per ni
        #pragma unroll
        for (int ni = 0; ni < 4; ++ni) {
            const int px = wn * 64 + ni * 16 + lrow;
            bf[ni] = *(const f16x8_t*)&Bs[cur][px * 32 + ((grp ^ (px & 3)) * 8)];
        }
        #pragma unroll
        for (int mi = 0; mi < 4; ++mi)
            #pragma unroll
            for (int ni = 0; ni < 4; ++ni)
                acc[mi][ni] = __builtin_amdgcn_mfma_f32_16x16x32_f16(
                    af[mi], bf[ni], acc[mi][ni], 0, 0, 0);

        // write-late: next B tile
        if (s < 7) {
            f16x8_t w0, w1;
            #pragma unroll
            for (int j = 0; j < 8; ++j) { w0[j] = (_Float16)r0[j]; w1[j] = (_Float16)r1[j]; }
            *(f16x8_t*)&Bs[nxt][bw0] = w0;
            *(f16x8_t*)&Bs[nxt][bw1] = w1;
        }

        // pass boundary: re-stage A with second K-half
        if (s == 3) {
            __syncthreads();               // all pass-0 A reads complete
            #pragma unroll
            for (int c = 0; c < 4; ++c) {
                float fl[16];
                #pragma unroll
                for (int q4 = 0; q4 < 4; ++q4) {
                    const float4 v = *(const float4*)(wrow + 128 + c * 16 + q4 * 4);
                    fl[q4 * 4 + 0] = v.x; fl[q4 * 4 + 1] = v.y;
                    fl[q4 * 4 + 2] = v.z; fl[q4 * 4 + 3] = v.w;
                }
                #pragma unroll
                for (int hs = 0; hs < 2; ++hs) {
                    const int slot = (khA >> 3) + c * 2 + hs;
                    f16x8_t w8;
                    #pragma unroll
                    for (int j = 0; j < 8; ++j) w8[j] = (_Float16)fl[hs * 8 + j];
                    *(f16x8_t*)&Ap[smA * 128 + ((slot ^ aswz) << 3)] = w8;
                }
            }
        }
        __syncthreads();
    }

    // epilogue: D row (m) = grp*4+reg, col (n) = l&15 — blocked fp16 stores
    #pragma unroll
    for (int ni = 0; ni < 4; ++ni) {
        const size_t ng = (size_t)(nt * 128 + wn * 64 + ni * 16 + lrow);
        #pragma unroll
        for (int mi = 0; mi < 4; ++mi) {
            f16x4_t hv;
            #pragma unroll
            for (int j = 0; j < 4; ++j) hv[j] = (_Float16)acc[mi][ni][j];
            const int chunk = mtl * 8 + wm * 4 + mi;     // 0..15
            *(f16x4_t*)&osel[((size_t)chunk * NTOT + ng) * 16 + lrow4] = hv;
        }
    }
}

// ---------- local grouped attention: q,k,v fp16 blocked; fp32 math ----------
__global__ __launch_bounds__(256) void loc_attn_kernel(
    const _Float16* __restrict__ qh, const _Float16* __restrict__ kh,
    const _Float16* __restrict__ vh, float* __restrict__ out)
{
    const int t   = threadIdx.x;
    const int bx0 = blockIdx.x;
    const int bx  = (bx0 & 7) * 128 + (bx0 >> 3);
    const int h = bx & 63;
    const int g = (bx >> 6) & 3;
    const int b = bx >> 8;

    const int wl  = t & 15;
    const int c   = (t >> 4) & 3;
    const int wid = t >> 6;
    const int w   = wid * 16 + wl;

    const int ck = g * 4 + c;                    // chunk index 0..15
    const size_t n = (size_t)b * HWSZ + h * 64 + w;

    float qf[16];
    {
        const _Float16* qp = &qh[((size_t)ck * NTOT + n) * 16];
        const f16x8_t q0 = *(const f16x8_t*)qp;
        const f16x8_t q1 = *(const f16x8_t*)(qp + 8);
        #pragma unroll
        for (int j = 0; j < 8; ++j) { qf[j] = (float)q0[j]; qf[8 + j] = (float)q1[j]; }
    }

    float logit[9];
    #pragma unroll
    for (int p = 0; p < 9; ++p) {
        const int dh = p / 3 - 1, dw = p % 3 - 1;
        const int hh = h + dh, ww2 = w + dw;
        float part = 0.f;
        if (hh >= 0 && hh < HH && ww2 >= 0 && ww2 < WW) {
            const size_t nn = (size_t)b * HWSZ + hh * 64 + ww2;
            const _Float16* kp = &kh[((size_t)ck * NTOT + nn) * 16];
            const f16x8_t k0 = *(const f16x8_t*)kp;
            const f16x8_t k1 = *(const f16x8_t*)(kp + 8);
            #pragma unroll
            for (int j = 0; j < 8; ++j)
                part += qf[j] * (float)k0[j] + qf[8 + j] * (float)k1[j];
        }
        part += __shfl_xor(part, 16, 64);
        part += __shfl_xor(part, 32, 64);
        logit[p] = part;
    }

    float mx = logit[0];
    #pragma unroll
    for (int p = 1; p < 9; ++p) mx = fmaxf(mx, logit[p]);
    float a[9];
    float s = 0.f;
    #pragma unroll
    for (int p = 0; p < 9; ++p) { a[p] = __expf(logit[p] - mx); s += a[p]; }
    const float inv = 1.f / s;
    #pragma unroll
    for (int p = 0; p < 9; ++p) a[p] *= inv;

    float acc[16];
    #pragma unroll
    for (int dd = 0; dd < 16; ++dd) acc[dd] = 0.f;
    #pragma unroll
    for (int p = 0; p < 9; ++p) {
        const int dh = p / 3 - 1, dw = p % 3 - 1;
        const int hh = h + dh, ww2 = w + dw;
        if (hh < 0 || hh >= HH || ww2 < 0 || ww2 >= WW) continue;
        const size_t nn = (size_t)b * HWSZ + hh * 64 + ww2;
        const _Float16* vp = &vh[((size_t)ck * NTOT + nn) * 16];
        const f16x8_t v0 = *(const f16x8_t*)vp;
        const f16x8_t v1 = *(const f16x8_t*)(vp + 8);
        const float ap = a[p];
        #pragma unroll
        for (int j = 0; j < 8; ++j) {
            acc[j]     += ap * (float)v0[j];
            acc[8 + j] += ap * (float)v1[j];
        }
    }

    const int obase = b * 256 + g * 64 + c * 16;
    const int off = h * 64 + w;
    #pragma unroll
    for (int dd = 0; dd < 16; ++dd)
        out[(size_t)(obase + dd) * HWSZ + off] = acc[dd];
}

extern "C" void kernel_launch(void* const* d_in, const int* in_sizes, int n_in,
                              void* d_out, int out_size, void* d_ws, size_t ws_size,
                              hipStream_t stream) {
    const float* x  = (const float*)d_in[0];
    const float* wq = (const float*)d_in[1];
    const float* bq = (const float*)d_in[2];
    const float* wk = (const float*)d_in[3];
    const float* bk = (const float*)d_in[4];
    const float* wv = (const float*)d_in[5];
    const float* bv = (const float*)d_in[6];
    float* out = (float*)d_out;

    char* ws = (char*)d_ws;
    _Float16* qh = (_Float16*)ws;                      //  8.39 MB
    _Float16* kh = (_Float16*)(ws + 8388608);          //  8.39 MB
    _Float16* vh = (_Float16*)(ws + 16777216);         //  8.39 MB

    qkv_gemm_kernel<<<dim3(768), 256, 0, stream>>>(x, wq, bq, wk, bk, wv, bv,
                                                   qh, kh, vh);
    loc_attn_kernel<<<dim3(1024), 256, 0, stream>>>(qh, kh, vh, out);
}